// Round 4
// baseline (732.368 us; speedup 1.0000x reference)
//
#include <hip/hip_runtime.h>
#include <hip/hip_bf16.h>

typedef unsigned short u16;
typedef __attribute__((ext_vector_type(8))) _Float16 half8;  // 8 fp16 in 4 VGPRs
typedef __attribute__((ext_vector_type(4))) float f32x4;

static __device__ __forceinline__ u16 f2h(float v) {
  return __builtin_bit_cast(u16, (_Float16)v);
}
static __device__ __forceinline__ float h2f(u16 u) {
  return (float)__builtin_bit_cast(_Float16, u);
}

// async global->LDS, 16B per lane. LDS dest = wave-uniform base + lane*16.
static __device__ __forceinline__ void gll16(const void* g, void* l) {
  __builtin_amdgcn_global_load_lds(
      (const __attribute__((address_space(1))) unsigned int*)g,
      (__attribute__((address_space(3))) unsigned int*)l, 16, 0, 0);
}

// ---------------------------------------------------------------------------
// gemm_bt: C[m][n] = sum_k A[m][k] * B[n][k]   (both operands K-contiguous,
// fp16). BMx128 tile (BM=128 or 64), BK=32, 256 threads = 4 waves (2x2),
// wave tile (BM/2)x64.
// ASPLIT: A given as hi+lo fp16; adds term Al*B.
// BSPLIT: B given as hi+lo fp16; adds term A*Bl.  (ll term dropped, ~2^-22)
// EPI: 0 = fp32 store; 1 = bias(m) + split2-fp16 store (Ch,Cl);
//      2 = fp32 + fp16 store; 3 = bias(n) + fp16 store; 4 = fp16 store
// ---------------------------------------------------------------------------
template <bool ASPLIT, bool BSPLIT, int EPI, int BM>
__global__ __launch_bounds__(256) void gemm_bt(
    const u16* __restrict__ A, const u16* __restrict__ Al,
    const u16* __restrict__ B, const u16* __restrict__ Bl,
    float* __restrict__ Cf, u16* __restrict__ Ch, u16* __restrict__ Cl,
    const float* __restrict__ bias0, const float* __restrict__ bias1,
    int biasSplit, int K, int lda, int ldb, int ldc,
    long long sA, long long sB, long long sC) {
  constexpr int ASZ = BM * 32;            // elems in one A region
  constexpr int NI = BM / 32;             // i-frag count per wave
  __shared__ __align__(16) u16 smA[(ASPLIT ? 2 : 1) * ASZ];
  __shared__ __align__(16) u16 smB[(BSPLIT ? 2 : 1) * 128 * 32];

  const int tid = threadIdx.x;
  const int wave = tid >> 6, lane = tid & 63;
  const int wr = wave >> 1, wc = wave & 1;
  const long long z = blockIdx.z;
  A += z * sA;
  B += z * sB;
  if (ASPLIT) Al += z * sA;
  if (BSPLIT) Bl += z * sB;
  const long long tM = (long long)blockIdx.y * BM;
  const long long tN = (long long)blockIdx.x * 128;
  const int r4 = lane >> 2, kc = lane & 3;

  const long long arow0 = (tM + wave * 16 + r4) * (long long)lda + kc * 8;
  const long long arow1 = arow0 + 64LL * lda;  // only used if BM==128
  const long long brow0 = (tN + wave * 16 + r4) * (long long)ldb + kc * 8;
  const long long brow1 = brow0 + 64LL * ldb;

  u16* lA0 = &smA[wave * 512];
  u16* lA1 = &smA[2048 + wave * 512];
  u16* lB0 = &smB[wave * 512];
  u16* lB1 = &smB[2048 + wave * 512];

  f32x4 acc[NI][4];
#pragma unroll
  for (int i = 0; i < NI; i++)
#pragma unroll
    for (int j = 0; j < 4; j++) acc[i][j] = f32x4{0.f, 0.f, 0.f, 0.f};

  const int quad = lane >> 4, mr = lane & 15;
  const int nk = K >> 5;
  for (int kt = 0; kt < nk; ++kt) {
    const long long ko = (long long)kt * 32;
    gll16(A + arow0 + ko, lA0);
    if constexpr (BM == 128) gll16(A + arow1 + ko, lA1);
    gll16(B + brow0 + ko, lB0);
    gll16(B + brow1 + ko, lB1);
    if constexpr (ASPLIT) {
      gll16(Al + arow0 + ko, &smA[ASZ + wave * 512]);
      if constexpr (BM == 128) gll16(Al + arow1 + ko, &smA[ASZ + 2048 + wave * 512]);
    }
    if constexpr (BSPLIT) {
      gll16(Bl + brow0 + ko, &smB[4096 + wave * 512]);
      gll16(Bl + brow1 + ko, &smB[4096 + 2048 + wave * 512]);
    }
    __syncthreads();  // drains vmcnt (global_load_lds) + barrier

    half8 a[NI], b[4];
#pragma unroll
    for (int i = 0; i < NI; i++)
      a[i] = *(const half8*)&smA[(wr * (BM / 2) + i * 16 + mr) * 32 + quad * 8];
#pragma unroll
    for (int j = 0; j < 4; j++)
      b[j] = *(const half8*)&smB[(wc * 64 + j * 16 + mr) * 32 + quad * 8];
#pragma unroll
    for (int i = 0; i < NI; i++)
#pragma unroll
      for (int j = 0; j < 4; j++)
        acc[i][j] = __builtin_amdgcn_mfma_f32_16x16x32_f16(a[i], b[j], acc[i][j], 0, 0, 0);

    if constexpr (ASPLIT) {
      half8 al[NI];
#pragma unroll
      for (int i = 0; i < NI; i++)
        al[i] = *(const half8*)&smA[ASZ + (wr * (BM / 2) + i * 16 + mr) * 32 + quad * 8];
#pragma unroll
      for (int i = 0; i < NI; i++)
#pragma unroll
        for (int j = 0; j < 4; j++)
          acc[i][j] = __builtin_amdgcn_mfma_f32_16x16x32_f16(al[i], b[j], acc[i][j], 0, 0, 0);
    }
    if constexpr (BSPLIT) {
      half8 bl[4];
#pragma unroll
      for (int j = 0; j < 4; j++)
        bl[j] = *(const half8*)&smB[4096 + (wc * 64 + j * 16 + mr) * 32 + quad * 8];
#pragma unroll
      for (int i = 0; i < NI; i++)
#pragma unroll
        for (int j = 0; j < 4; j++)
          acc[i][j] = __builtin_amdgcn_mfma_f32_16x16x32_f16(a[i], bl[j], acc[i][j], 0, 0, 0);
    }
    __syncthreads();
  }

  // epilogue: C/D map (verified): col = lane&15, row = quad*4 + reg
#pragma unroll
  for (int i = 0; i < NI; i++) {
#pragma unroll
    for (int j = 0; j < 4; j++) {
      const long long gn = tN + wc * 64 + j * 16 + mr;
#pragma unroll
      for (int p = 0; p < 4; p++) {
        const long long gm = tM + wr * (BM / 2) + i * 16 + quad * 4 + p;
        float v = acc[i][j][p];
        if constexpr (EPI == 1) v += (gm < biasSplit) ? bias0[gm] : bias1[gm - biasSplit];
        if constexpr (EPI == 3) v += (gn < biasSplit) ? bias0[gn] : bias1[gn - biasSplit];
        const long long off = z * sC + gm * ldc + gn;
        if constexpr (EPI == 0) {
          Cf[off] = v;
        } else if constexpr (EPI == 1) {
          u16 h = f2h(v);
          Ch[off] = h;
          Cl[off] = f2h(v - h2f(h));
        } else if constexpr (EPI == 2) {
          Cf[off] = v;
          Ch[off] = f2h(v);
        } else {
          Ch[off] = f2h(v);
        }
      }
    }
  }
  (void)biasSplit;
}

// ---------------------------------------------------------------------------
// merged prep kernel. Block ranges:
//  [0,6912)        : W split2-fp16  (x4 vectorized)
//  [6912,6976)     : Wp -> fp16     (x4)
//  [6976,27712)    : im2col -> fp16 (x4)
//  [27712,36928)   : xt transpose
// ---------------------------------------------------------------------------
__global__ void prep_kernel(const float* __restrict__ x,
                            const float* __restrict__ Wqc, const float* __restrict__ Wkc,
                            const float* __restrict__ Wqp, const float* __restrict__ Wkp,
                            u16* __restrict__ Wh, u16* __restrict__ Wl,
                            u16* __restrict__ Wp, u16* __restrict__ P,
                            u16* __restrict__ xt) {
  __shared__ float t[32][33];
  const int bid = blockIdx.x;
  const int tid = threadIdx.x;
  if (bid < 6912) {
    // W split2: 1536x4608 floats, 4 per thread (4608%4==0 -> same row)
    int i4 = (bid * 256 + tid) * 4;
    int n = i4 / 4608;
    const float* src = (n < 1024) ? (Wqc + i4) : (Wkc + (i4 - 1024 * 4608));
    float4 v = *(const float4*)src;
    u16 h0 = f2h(v.x), h1 = f2h(v.y), h2 = f2h(v.z), h3 = f2h(v.w);
    *(ushort4*)(Wh + i4) = ushort4{h0, h1, h2, h3};
    *(ushort4*)(Wl + i4) = ushort4{f2h(v.x - h2f(h0)), f2h(v.y - h2f(h1)),
                                   f2h(v.z - h2f(h2)), f2h(v.w - h2f(h3))};
  } else if (bid < 6976) {
    // Wqp||Wkp -> fp16 [dd][c]: 128x512 floats, 4 per thread (512%4==0)
    int i4 = ((bid - 6912) * 256 + tid) * 4;
    int d = i4 >> 9;
    const float* src = (d < 64) ? (Wqp + i4) : (Wkp + (i4 - 64 * 512));
    float4 v = *(const float4*)src;
    *(ushort4*)(Wp + i4) = ushort4{f2h(v.x), f2h(v.y), f2h(v.z), f2h(v.w)};
  } else if (bid < 27712) {
    // im2col stride-2 3x3 pad-1: P[(b,oy,ox)][(c,ky,kx)], 4 k per thread
    int base = ((bid - 6976) * 256 + tid) * 4;  // < 4608*4608
    int m = base / 4608;
    int k0 = base % 4608;  // 4 consecutive k stay in row (4608%4==0)
    int ox = m % 24, t2 = m / 24;
    int oy = t2 % 24, b = t2 / 24;
    u16 r[4];
#pragma unroll
    for (int j = 0; j < 4; j++) {
      int k = k0 + j;
      int kx = k % 3, tt = k / 3;
      int ky = tt % 3, c = tt / 3;
      int ix = 2 * ox - 1 + kx, iy = 2 * oy - 1 + ky;
      float v = 0.f;
      if (ix >= 0 && ix < 48 && iy >= 0 && iy < 48)
        v = x[((b * 512 + c) * 48 + iy) * 48 + ix];
      r[j] = f2h(v);
    }
    *(ushort4*)(P + base) = ushort4{r[0], r[1], r[2], r[3]};
  } else {
    // xt: x (b,c,sp) -> xt[(b,sp)][c] fp16
    int id2 = bid - 27712;  // < 9216 = 8 * 16 * 72
    int b = id2 / 1152;
    int rem = id2 % 1152;
    int sp0 = (rem % 72) * 32, c0 = (rem / 72) * 32;
    int tx = tid & 31, ty = tid >> 5;  // 32 x 8
#pragma unroll
    for (int k = 0; k < 4; k++) {
      int c = c0 + ty + k * 8;
      t[ty + k * 8][tx] = x[((long long)(b * 512 + c)) * 2304 + sp0 + tx];
    }
    __syncthreads();
#pragma unroll
    for (int k = 0; k < 4; k++) {
      int sp = sp0 + ty + k * 8;
      xt[((long long)b * 2304 + sp) * 512 + c0 + tx] = f2h(t[tx][ty + k * 8]);
    }
  }
}

// CAM softmax, wave-per-row: attn = exp(rowmin - e)/sum (== softmax(max-e))
__global__ void softmax_cam(const float* __restrict__ E, u16* __restrict__ attn) {
  const long long r = (long long)blockIdx.x * 4 + (threadIdx.x >> 6);  // 8192 rows
  const int lane = threadIdx.x & 63;
  const float* e = E + r * 512;
  float v[8];
#pragma unroll
  for (int k = 0; k < 8; k++) v[k] = e[lane + 64 * k];
  float mn = v[0];
#pragma unroll
  for (int k = 1; k < 8; k++) mn = fminf(mn, v[k]);
#pragma unroll
  for (int o = 32; o; o >>= 1) mn = fminf(mn, __shfl_xor(mn, o));
  float s = 0.f;
#pragma unroll
  for (int k = 0; k < 8; k++) {
    v[k] = __expf(mn - v[k]);
    s += v[k];
  }
#pragma unroll
  for (int o = 32; o; o >>= 1) s += __shfl_xor(s, o);
  float inv = 1.f / s;
#pragma unroll
  for (int k = 0; k < 8; k++) attn[r * 512 + lane + 64 * k] = f2h(v[k] * inv);
}

// PAM softmax, wave-per-row: in-place row softmax over 2304 cols (fp16)
__global__ void softmax_pam(u16* __restrict__ EP) {
  const long long r = (long long)blockIdx.x * 4 + (threadIdx.x >> 6);  // 18432 rows
  const int lane = threadIdx.x & 63;
  u16* e = EP + r * 2304;
  float v[36];
#pragma unroll
  for (int k = 0; k < 36; k++) v[k] = h2f(e[lane + 64 * k]);
  float mx = v[0];
#pragma unroll
  for (int k = 1; k < 36; k++) mx = fmaxf(mx, v[k]);
#pragma unroll
  for (int o = 32; o; o >>= 1) mx = fmaxf(mx, __shfl_xor(mx, o));
  float s = 0.f;
#pragma unroll
  for (int k = 0; k < 36; k++) {
    v[k] = __expf(v[k] - mx);
    s += v[k];
  }
#pragma unroll
  for (int o = 32; o; o >>= 1) s += __shfl_xor(s, o);
  float inv = 1.f / s;
#pragma unroll
  for (int k = 0; k < 36; k++) e[lane + 64 * k] = f2h(v[k] * inv);
}

// ---------------------------------------------------------------------------
extern "C" void kernel_launch(void* const* d_in, const int* in_sizes, int n_in,
                              void* d_out, int out_size, void* d_ws, size_t ws_size,
                              hipStream_t stream) {
  const float* x   = (const float*)d_in[0];
  const float* Wqc = (const float*)d_in[1];
  const float* bqc = (const float*)d_in[2];
  const float* Wkc = (const float*)d_in[3];
  const float* bkc = (const float*)d_in[4];
  const float* Wqp = (const float*)d_in[5];
  const float* bqp = (const float*)d_in[6];
  const float* Wkp = (const float*)d_in[7];
  const float* bkp = (const float*)d_in[8];
  float* outc = (float*)d_out;                 // (8,1024,2304) fp32
  float* outp = outc + 8LL * 1024 * 2304;      // (8,1024,48,48) fp32

  if (ws_size < 195166208ULL) return;  // need ~186.1 MB scratch

  char* ws = (char*)d_ws;
  // lifetime-aliased arena (fp16 buffers as u16):
  u16*   P    = (u16*)(ws + 0);             // 4608x4608       [dead after conv]
  u16*   Wh   = (u16*)(ws + 42467328LL);    // 1536x4608 hi    [dead after conv]
  u16*   Wl   = (u16*)(ws + 56623104LL);    // 1536x4608 lo    [dead after conv]
  u16*   EP   = (u16*)(ws + 0);             // 8x2304x2304     [aliases P+W]
  u16*   qcth = (u16*)(ws + 84934656LL);    // 1536x4608 hi    [dead after energy]
  u16*   qctl = (u16*)(ws + 99090432LL);    // 1536x4608 lo    [dead after energy]
  u16*   pp   = (u16*)(ws + 84934656LL);    // 18432x128       [aliases qct]
  float* E    = (float*)(ws + 113246208LL); // 8x1024x512 fp32 [dead after softmax_cam]
  u16*   attn = (u16*)(ws + 130023424LL);   // 8x1024x512      [dead after out_c]
  u16*   xt   = (u16*)(ws + 138412032LL);   // 18432x512       [dead after pp gemm]
  u16*   ocb  = (u16*)(ws + 157286400LL);   // 8x1024x2304     [till end]
  u16*   Wp   = (u16*)(ws + 195035136LL);   // 128x512

  // all input prep in one launch
  prep_kernel<<<36928, 256, 0, stream>>>(x, Wqc, Wkc, Wqp, Wkp, Wh, Wl, Wp, P, xt);

  // CAM convs (W-split 2-term): qct[ch][(b,sp)] = (Wh+Wl)*P^T + bias,
  // split2-fp16 out
  gemm_bt<true, false, 1, 128><<<dim3(36, 12, 1), 256, 0, stream>>>(
      Wh, Wl, P, nullptr, nullptr, qcth, qctl, bqc, bkc, 1024,
      4608, 4608, 4608, 4608, 0, 0, 0);

  // energy[b][q][c] fp32 (3-term: hh + lh + hl), BM=64 -> 512 blocks
  gemm_bt<true, true, 0, 64><<<dim3(4, 16, 8), 256, 0, stream>>>(
      qcth, qctl, qcth + 1024LL * 4608, qctl + 1024LL * 4608,
      E, nullptr, nullptr,
      nullptr, nullptr, 0, 576, 4608, 4608, 512, 576, 576, 524288);

  softmax_cam<<<2048, 256, 0, stream>>>(E, attn);

  // out_c[b][q][sp] = attn @ x  (fp32 -> d_out, fp16 -> ocb)
  gemm_bt<false, false, 2, 128><<<dim3(18, 8, 8), 256, 0, stream>>>(
      attn, nullptr, xt, nullptr, outc, ocb, nullptr,
      nullptr, nullptr, 0, 512, 512, 512, 2304, 524288, 1179648, 2359296);

  // qp/kp 1x1 convs: pp[(b,sp)][dd] = xt @ Wp^T + bias(dd), BM=64 -> 288 blocks
  gemm_bt<false, false, 3, 64><<<dim3(1, 288, 1), 256, 0, stream>>>(
      xt, nullptr, Wp, nullptr, nullptr, pp, nullptr,
      bqp, bkp, 64, 512, 512, 512, 128, 0, 0, 0);

  // energy_p[b][i][j] = qp(i) . kp(j), K=64, fp16 out
  gemm_bt<false, false, 4, 128><<<dim3(18, 18, 8), 256, 0, stream>>>(
      pp, nullptr, pp + 64, nullptr, nullptr, EP, nullptr,
      nullptr, nullptr, 0, 64, 128, 128, 2304, 294912, 294912, 5308416);

  softmax_pam<<<4608, 256, 0, stream>>>(EP);

  // out_p[b][q][m] = out_c @ attn_p^T (fp32 -> d_out)
  gemm_bt<false, false, 0, 128><<<dim3(18, 8, 8), 256, 0, stream>>>(
      ocb, nullptr, EP, nullptr, outp, nullptr, nullptr,
      nullptr, nullptr, 0, 2304, 2304, 2304, 2304, 2359296, 5308416, 2359296);

  (void)in_sizes; (void)n_in; (void)out_size;
}